// Round 11
// baseline (170.186 us; speedup 1.0000x reference)
//
#include <hip/hip_runtime.h>
#include <hip/hip_bf16.h>

// CorrelationLayerCosineSimilarity via banded bf16 MFMA GEMM.
// out[b,d,h,w] = dot_c(x1,x2p shifted d) / max(n1*n2, 1e-6); B=4,C=256,H=128,W=256,D=41.
//
// Round 11: ROUND-10 STRUCTURE, NORM-RANGE BUG FIXED.
//  - R10's only defect: `if (tid < 296)` zero-init / sqrt passes with a
//    256-thread block -> indices 256..295 (n2sq of the overlap region
//    w' in [128,168)) were garbage-based and never sqrt'd (absmax 0.286).
//    Fixed with strided loops over 296 elements.
//  - grid 1024 = (b, h, w-half); 256-thr blocks (4 waves). 4 blocks/CU
//    -> 4 INDEPENDENT 4-wave barrier groups per CU (R6 had 2 lock-step
//    8-wave groups; R4/R9 proved occupancy & prefetch depth aren't the
//    lever — independent groups overlapping each other's stalls are).
//  - Per block: w in [128*half, +128); x2 cols +40 overlap (+21 MB reads).
//  - Wave v owns w-tiles {v, v+4} x 4 c-tiles (8 MFMA / K-step, as R6).
//  - Staging: lane (q=l&31, h2=l>>5) of wave v loads channels 8v+4h2+j,
//    w-quad q (x1, x2A) and w-quad 32+q for q<10 (x2B). fp32 -> RNE bf16
//    -> 4x4 transpose -> uint2 LDS writes. 1-deep prefetch.
//  - Raw-barrier phase boundaries (R6): sched_barrier(0) + own lgkmcnt(0)
//    drain + s_barrier; vmem prefetch stays in flight across barriers.
//
// LDS (25504B): A[wl 0..127][kc 0..31] bf16 rows of 80B (4x16B slots + pad
// slot; logical slot s of row r at physical (s+r)%5 -> conflict-free b128
// frag reads). B[wl' 0..175][kc] same; rows 168..175 never written (feed
// only discarded d>40 outputs; epilogue reads Sw col mm+d <= 55 < 56).
// Norms (296 f32) at NBASE. Epilogue: per-wave 16x66 f32 transpose
// (overlays A/B) -> normalize -> coalesced [d][w] f32x4 stores.

#define B_   4
#define C_   256
#define H_   128
#define W_   256
#define ND_  41
#define HW_  (H_ * W_)
#define CHW_ (C_ * HW_)
#define EPS_ 1e-6f

typedef __attribute__((ext_vector_type(4))) float f32x4;
typedef __attribute__((ext_vector_type(8))) short bf16x8;

#define ABASE 0
#define BBASE 10240            // A: 128*80
#define NBASE 24320            // B ends: BBASE + 176*80
#define LDSZ  25504            // + 296 f32 norms

// Phase boundary: own-lgkm drain + raw barrier, vmem loads stay in flight.
#define PHASE_BAR() do {                                         \
    __builtin_amdgcn_sched_barrier(0);                           \
    asm volatile("s_waitcnt lgkmcnt(0)" ::: "memory");           \
    __builtin_amdgcn_s_barrier();                                \
    __builtin_amdgcn_sched_barrier(0);                           \
  } while (0)

__device__ __forceinline__ unsigned bfr(float x) {   // fp32 -> bf16 bits, RNE
  unsigned u = __builtin_bit_cast(unsigned, x);
  return (u + 0x7fffu + ((u >> 16) & 1u)) >> 16;
}

__global__ __launch_bounds__(256, 4)
void corr_mfma(const float* __restrict__ x1, const float* __restrict__ x2,
               float* __restrict__ out) {
  __shared__ __align__(16) char lds[LDSZ];

  const int tid = threadIdx.x;
  const int l   = tid & 63;
  const int v   = tid >> 6;          // wave id, 0..3
  const int m   = l & 15;
  const int g   = l >> 4;
  const int q   = l & 31;            // staging w-quad
  const int h2  = l >> 5;            // staging channel-half

  const int r    = blockIdx.x;
  const int half = r & 1;
  const int hh   = (r >> 1) & (H_ - 1);
  const int b    = r >> 8;
  const int wb   = 128 * half;       // block's w origin

  const float* X1 = x1 + b * CHW_ + hh * W_ + wb;
  const float* X2 = x2 + b * CHW_ + hh * W_ + wb;

  // ---- prologue: zero norm accumulators (296 > 256: strided!) ----
  for (int i = tid; i < 296; i += 256) ((float*)(lds + NBASE))[i] = 0.f;

  // ---- loop-invariant addresses ----
  int wadrA[4], wadrBa[4], wadrBb[4];
#pragma unroll
  for (int jj = 0; jj < 4; ++jj) {
    int wa = 4 * q + jj;
    wadrA[jj]  = ABASE + wa * 80 + ((v + wa) % 5) * 16 + 8 * h2;
    wadrBa[jj] = BBASE + wa * 80 + ((v + wa) % 5) * 16 + 8 * h2;
    int wbb = 128 + 4 * q + jj;
    wadrBb[jj] = BBASE + wbb * 80 + ((v + wbb) % 5) * 16 + 8 * h2;
  }
  int adrA[2], adrB[2][4];
#pragma unroll
  for (int i = 0; i < 2; ++i) {
    int wt = v + 4 * i;
    int rowA = 16 * wt + m;
    adrA[i] = ABASE + rowA * 80 + ((g + rowA) % 5) * 16;
#pragma unroll
    for (int c = 0; c < 4; ++c) {
      int col = 16 * (wt + c) + m;    // <= 175
      adrB[i][c] = BBASE + col * 80 + ((g + col) % 5) * 16;
    }
  }

  f32x4 acc[2][4];
#pragma unroll
  for (int i = 0; i < 2; ++i)
#pragma unroll
    for (int c = 0; c < 4; ++c) acc[i][c] = (f32x4){0.f, 0.f, 0.f, 0.f};
  float ssq1[4]  = {0.f, 0.f, 0.f, 0.f};
  float ssq2a[4] = {0.f, 0.f, 0.f, 0.f};
  float ssq2b[4] = {0.f, 0.f, 0.f, 0.f};

  const bool ldb = (q < 10) && (half == 0);   // x2B real-load predicate

  // ---- single register set, 1-deep prefetch ----
  f32x4 r1[4], r2a[4], r2b[4];
  auto loadset = [&](int ks) {
    const float* p1 = X1 + (ks * 32 + 8 * v + 4 * h2) * HW_ + 4 * q;
    const float* p2 = X2 + (ks * 32 + 8 * v + 4 * h2) * HW_ + 4 * q;
#pragma unroll
    for (int j = 0; j < 4; ++j) {
      r1[j]  = *(const f32x4*)(p1 + j * HW_);
      r2a[j] = *(const f32x4*)(p2 + j * HW_);
      r2b[j] = ldb ? *(const f32x4*)(p2 + j * HW_ + 128)
                   : (f32x4){0.f, 0.f, 0.f, 0.f};
    }
  };

  loadset(0);

  for (int ks = 0; ks < 8; ++ks) {
    PHASE_BAR();                      // B1: prev tile's frag reads done
    // ---- pack phase: ssq + bf16 pack + transposed LDS writes ----
#pragma unroll
    for (int jj = 0; jj < 4; ++jj) {
      ssq1[jj]  += r1[0][jj] * r1[0][jj] + r1[1][jj] * r1[1][jj]
                 + r1[2][jj] * r1[2][jj] + r1[3][jj] * r1[3][jj];
      ssq2a[jj] += r2a[0][jj] * r2a[0][jj] + r2a[1][jj] * r2a[1][jj]
                 + r2a[2][jj] * r2a[2][jj] + r2a[3][jj] * r2a[3][jj];
      ssq2b[jj] += r2b[0][jj] * r2b[0][jj] + r2b[1][jj] * r2b[1][jj]
                 + r2b[2][jj] * r2b[2][jj] + r2b[3][jj] * r2b[3][jj];
      uint2 q1, q2;
      q1.x = bfr(r1[0][jj]) | (bfr(r1[1][jj]) << 16);
      q1.y = bfr(r1[2][jj]) | (bfr(r1[3][jj]) << 16);
      q2.x = bfr(r2a[0][jj]) | (bfr(r2a[1][jj]) << 16);
      q2.y = bfr(r2a[2][jj]) | (bfr(r2a[3][jj]) << 16);
      *(uint2*)(lds + wadrA[jj])  = q1;
      *(uint2*)(lds + wadrBa[jj]) = q2;
      if (q < 10) {                   // x2B rows 128..167 (zeros when half=1)
        uint2 q3;
        q3.x = bfr(r2b[0][jj]) | (bfr(r2b[1][jj]) << 16);
        q3.y = bfr(r2b[2][jj]) | (bfr(r2b[3][jj]) << 16);
        *(uint2*)(lds + wadrBb[jj]) = q3;
      }
    }
    if (ks < 7) loadset(ks + 1);      // refill; in flight across barriers
    PHASE_BAR();                      // B2: tile ready
    // ---- compute: 10 ds_read_b128 + 8 MFMA ----
    bf16x8 a0 = *(const bf16x8*)(lds + adrA[0]);
    bf16x8 a1 = *(const bf16x8*)(lds + adrA[1]);
#pragma unroll
    for (int c = 0; c < 4; ++c) {
      bf16x8 b0 = *(const bf16x8*)(lds + adrB[0][c]);
      acc[0][c] = __builtin_amdgcn_mfma_f32_16x16x32_bf16(a0, b0, acc[0][c], 0, 0, 0);
    }
#pragma unroll
    for (int c = 0; c < 4; ++c) {
      bf16x8 b1 = *(const bf16x8*)(lds + adrB[1][c]);
      acc[1][c] = __builtin_amdgcn_mfma_f32_16x16x32_bf16(a1, b1, acc[1][c], 0, 0, 0);
    }
  }

  // ---- norms: LDS atomic reduce, then sqrt in place (296: strided!) ----
  float* nsq = (float*)(lds + NBASE);   // n1sq[128] | n2sq[168]
#pragma unroll
  for (int jj = 0; jj < 4; ++jj) {
    atomicAdd(nsq + 4 * q + jj, ssq1[jj]);
    atomicAdd(nsq + 128 + 4 * q + jj, ssq2a[jj]);
    if (q < 10) atomicAdd(nsq + 256 + 4 * q + jj, ssq2b[jj]);
  }
  __syncthreads();                    // all frag reads of A/B also done
  for (int i = tid; i < 296; i += 256) nsq[i] = sqrtf(nsq[i]);
  __syncthreads();

  // ---- epilogue: per-wave transpose -> normalize -> coalesced stores ----
  float* Sw  = (float*)(lds + v * 4224);   // 16 x 66 f32, overlays A/B
  float* n1s = nsq;                        // [128] local w
  float* n2s = nsq + 128;                  // [168] local w'
  const int wq = l & 3, dd = l >> 2;
#pragma unroll
  for (int i = 0; i < 2; ++i) {
    int wt = v + 4 * i;
#pragma unroll
    for (int c = 0; c < 4; ++c)
#pragma unroll
      for (int rr = 0; rr < 4; ++rr)
        Sw[(4 * g + rr) * 66 + 16 * c + m] = acc[i][c][rr];
    // wave-internal LDS RAW: in-order per wave + compiler lgkm waits
    const int w0 = 16 * wt + 4 * wq;       // local
#pragma unroll
    for (int p = 0; p < 3; ++p) {
      int d = 16 * p + dd;
      if (d <= 40) {
        f32x4 o;
#pragma unroll
        for (int j = 0; j < 4; ++j) {
          int mm = 4 * wq + j;
          float dot = Sw[mm * 66 + mm + d];
          o[j] = dot / fmaxf(n1s[w0 + j] * n2s[w0 + j + d], EPS_);
        }
        *(f32x4*)(out + ((b * ND_ + d) * H_ + hh) * W_ + wb + w0) = o;
      }
    }
  }
}

extern "C" void kernel_launch(void* const* d_in, const int* in_sizes, int n_in,
                              void* d_out, int out_size, void* d_ws, size_t ws_size,
                              hipStream_t stream) {
  const float* x1 = (const float*)d_in[0];
  const float* x2 = (const float*)d_in[1];
  float* out = (float*)d_out;
  dim3 grid(B_ * H_ * 2);
  dim3 block(256);
  hipLaunchKernelGGL(corr_mfma, grid, block, 0, stream, x1, x2, out);
}